// Round 13
// baseline (1071.266 us; speedup 1.0000x reference)
//
#include <hip/hip_runtime.h>
#include <stdint.h>

// Problem constants (match reference)
#define NB   8
#define NP   16384
#define NG   512      // NUM_GROUPS
#define GS   32       // GROUP_SIZE
#define UPK  512      // UPSCALE_K
#define CTX  256      // CONTEXT

// float32 output layout (flat element offsets):
// groups (8,256,32,4) | centers (8,256,4) | emb_mask (8,256) | point_mask (8,256,32)
#define OFF_CENTERS (NB*CTX*GS*4)            // 262144
#define OFF_EMB     (OFF_CENTERS + NB*CTX*4) // 270336
#define OFF_PMASK   (OFF_EMB + NB*CTX)       // 272384

// Workspace layout (bytes)
#define WS_CENTERS   0                        // float4[8*512]  = 65536
#define WS_GLEN      65536                    // int[8]         = 32
#define WS_SLOT      65600                    // u64[8][512]    = 32768
#define WS_CNT       98368                    // u32[8][512]    = 16384
#define WS_ZERO_FROM 65536
#define WS_ZERO_LEN  (114752 - 65536)

typedef unsigned long long u64;
typedef unsigned int u32;

// Monotonic float->uint key (full-range; needed for energies which can be <0)
__device__ __forceinline__ u32 fkey(float f) {
  union { float f; u32 u; } v; v.f = f;
  u32 s = v.u;
  return s ^ ((s & 0x80000000u) ? 0xFFFFFFFFu : 0x80000000u);
}

// Strictly-unfused f32 squared distance, op order = np: ((dx*dx+dy*dy)+dz*dz).
// _rn intrinsics forbid FMA contraction (hipcc defaults -ffp-contract=fast).
__device__ __forceinline__ float dist2(float ax, float ay, float az,
                                       float bx, float by, float bz) {
  float dx = __fsub_rn(ax, bx);
  float dy = __fsub_rn(ay, by);
  float dz = __fsub_rn(az, bz);
  return __fadd_rn(__fadd_rn(__fmul_rn(dx, dx), __fmul_rn(dy, dy)),
                   __fmul_rn(dz, dz));
}

// u64 max-combine with a DPP-moved copy (bound_ctrl=false keeps own value
// for invalid sources -> max no-op there). Proven since R8 (absmax 0).
template<int CTRL, int RM>
__device__ __forceinline__ u64 dpp_max_u64(u64 k) {
  int lo = (int)(u32)k, hi = (int)(u32)(k >> 32);
  int mlo = __builtin_amdgcn_update_dpp(lo, lo, CTRL, RM, 0xf, false);
  int mhi = __builtin_amdgcn_update_dpp(hi, hi, CTRL, RM, 0xf, false);
  u64 o = ((u64)(u32)mhi << 32) | (u32)mlo;
  return o > k ? o : k;
}

__device__ __forceinline__ u64 wave_max_u64(u64 k) {
  k = dpp_max_u64<0x111, 0xf>(k);   // row_shr:1
  k = dpp_max_u64<0x112, 0xf>(k);   // row_shr:2
  k = dpp_max_u64<0x114, 0xf>(k);   // row_shr:4
  k = dpp_max_u64<0x118, 0xf>(k);   // row_shr:8
  k = dpp_max_u64<0x142, 0xa>(k);   // row_bcast:15
  k = dpp_max_u64<0x143, 0xc>(k);   // row_bcast:31 -> lane63 = wave max
  return k;
}

__device__ __forceinline__ u64 read_lane_u64(u64 k, int lane) {
  u32 lo = (u32)__builtin_amdgcn_readlane((int)(u32)k, lane);
  u32 hi = (u32)__builtin_amdgcn_readlane((int)(u32)(k >> 32), lane);
  return ((u64)hi << 32) | lo;
}

// ---------------------------------------------------------------------------
// Kernel 1: farthest point sampling, multi-block. 4 blocks per batch (32
// blocks total, all co-resident on 256 CUs), each owning a 4096-point
// stripe (8 pts/thread -> no register pressure). Per iteration: stripe-local
// u64 argmax (wave DPP + LDS + DPP merge, 1 barrier), then a device-scope
// global handshake: atomicMax(key) -> threadfence -> atomicAdd(arrive);
// one spinner/block polls with L2-coherent RMW reads until all 4 posted,
// reads the global winner key (atomic RMW read), broadcasts via LDS
// (barrier 2). Per-iteration slots (memset to 0 pre-launch) -> no reset
// race. Key = (distbits<<32)|~gidx: u64 max == (max dist, min index) ==
// np.argmax first occurrence. Invalid points alias p[0] -> mind == 0 from
// iter 1, never win. Distances >= 0, no NaN -> f32 bits u32-monotonic.
// ---------------------------------------------------------------------------
#define FB    4                      // blocks per batch
#define FPS_T 512
#define PPT   (NP / (FPS_T * FB))    // 8 points per thread
#define STRIDE NP_OVER_FB
#define NP_OVER_FB (NP / FB)         // 4096

__global__ __launch_bounds__(FPS_T)
void fps_kernel(const float4* __restrict__ pts, const int* __restrict__ lengths,
                float4* __restrict__ centers_ws, int* __restrict__ group_len,
                u64* __restrict__ slots, u32* __restrict__ cnts,
                float* __restrict__ out)
{
  const int blk  = blockIdx.x;
  const int b    = blk & (NB - 1);    // batch; blocks b, b+8, b+16, b+24
  const int sub  = blk >> 3;          // stripe 0..3 (same XCD round-robin)
  const int tid  = threadIdx.x;
  const int lane = tid & 63;
  const int wave = tid >> 6;          // 8 waves
  const int base = sub * NP_OVER_FB;
  const float4* p = pts + (size_t)b * NP;
  const int len = lengths[b];
  if (sub == 0 && tid == 0) group_len[b] = 0;

  u64* __restrict__ slot = slots + b * NG;
  u32* __restrict__ cnt  = cnts  + b * NG;

  const float4 q0 = p[0];
  float px[PPT], py[PPT], pz[PPT], mind[PPT];
#pragma unroll
  for (int j = 0; j < PPT; j++) {
    int i = base + tid + j * FPS_T;   // strided ownership -> coalesced loads
    float4 q = p[i];
    if (i >= len) q = q0;             // invalid -> alias of p[0]
    px[j] = q.x; py[j] = q.y; pz[j] = q.z;
    mind[j] = 1e10f;
  }

  __shared__ u64 sred[2][8];          // parity-buffered
  __shared__ int s_last;
  __shared__ int s_centers[NG];
  if (tid == 0) s_centers[0] = 0;     // start index = 0

  int last = 0;
  for (int it = 1; it < NG; it++) {
    float4 lp = p[last];              // uniform -> scalar load, L2-served
    float tmax = -1.0f; int tj = 0;
#pragma unroll
    for (int j = 0; j < PPT; j++) {
      float d = dist2(px[j], py[j], pz[j], lp.x, lp.y, lp.z);
      float m = fminf(mind[j], d);
      mind[j] = m;
      bool c = m > tmax;              // strict > keeps earliest j
      tmax = c ? m : tmax;
      tj   = c ? j : tj;
    }
    int gidx = base + tid + (tj << 9);  // global point index
    u64 key = ((u64)__float_as_uint(tmax) << 32) | (u32)(~gidx);
    key = wave_max_u64(key);          // lane 63 = wave winner
    u64 wkey = read_lane_u64(key, 63);
    if (lane == 0) sred[it & 1][wave] = wkey;
    __syncthreads();                  // barrier 1
    u64 k2 = sred[it & 1][lane & 7];  // 8 slots replicated every 8 lanes
    k2 = dpp_max_u64<0x111, 0xf>(k2);
    k2 = dpp_max_u64<0x112, 0xf>(k2);
    k2 = dpp_max_u64<0x114, 0xf>(k2); // lane7 = block winner
    u64 bk = read_lane_u64(k2, 7);

    if (tid == 0) {                   // cross-block handshake (device scope)
      atomicMax(&slot[it], bk);
      __threadfence();
      atomicAdd(&cnt[it], 1u);
      int guard = 0;
      while (atomicAdd(&cnt[it], 0u) < FB && ++guard < (1 << 26)) {
        __builtin_amdgcn_s_sleep(2);
      }
      u64 g = atomicAdd(&slot[it], 0ull);   // coherent RMW read
      s_last = (int)(~(u32)g) & (NP - 1);
    }
    __syncthreads();                  // barrier 2
    last = s_last;
    if (tid == 0) s_centers[it] = last;
  }
  __syncthreads();

  if (sub == 0) {                     // FPS_T == NG == 512: 1 center/thread
    int ci = s_centers[tid] & (NP - 1);
    float4 q = p[ci];
    centers_ws[b * NG + tid] = q;
    if (tid < CTX) {
      ((float4*)(out + OFF_CENTERS))[b * CTX + tid] = q;
    }
  }
}

// ---------------------------------------------------------------------------
// Kernel 2: ball query (first-512-by-index candidates, strict-f32 test)
// + top-32 by energy. Swizzled so batch b owns XCD b (blk&7) -> per-XCD
// L2-resident point data. g >= CTX groups take a count-only fast path.
// Heavy path: ballot masks -> shfl_up prefix scan (1 barrier) -> compact ->
// single-wave barrier-free top-32 (u64 key = fkeyE<<32 | ~pos).
// ---------------------------------------------------------------------------
#define BQ_T 256

__global__ __launch_bounds__(BQ_T)
void group_kernel(const float4* __restrict__ pts, const int* __restrict__ lengths,
                  const float4* __restrict__ centers_ws, int* __restrict__ group_len,
                  float* __restrict__ out)
{
  const int blk  = blockIdx.x;
  const int b    = blk & (NB - 1);    // XCD affinity (blockIdx % 8 round-robin)
  const int g    = blk >> 3;
  const int tid  = threadIdx.x;
  const int lane = tid & 63;
  const int wave = tid >> 6;
  const float4* p = pts + (size_t)b * NP;
  const int len = lengths[b];
  const float4 cc = centers_ws[b * NG + g];

  __shared__ u64 masks[256];          // per-64-chunk in-radius bitmasks
  __shared__ u32 scnt[256];
  __shared__ u32 spre[256];
  __shared__ u32 swsum[4];
  __shared__ float candE[UPK];
  __shared__ int   candI[UPK];
  __shared__ int   s_T, s_pl;
  __shared__ int   s_win[GS];

  if (g >= CTX) {                     // count-only: is this group full?
    u32 c = 0;
    for (int step = 0; step < 64; step++) {
      int i = step * 256 + tid;
      if (i < len) {
        float4 q = p[i];
        float d = dist2(cc.x, cc.y, cc.z, q.x, q.y, q.z);
        c += (d < 0.25f) ? 1u : 0u;
      }
    }
#pragma unroll
    for (int off = 32; off; off >>= 1) c += __shfl_down(c, (unsigned)off, 64);
    if (lane == 0) swsum[wave] = c;
    __syncthreads();
    if (tid == 0) {
      u32 total = swsum[0] + swsum[1] + swsum[2] + swsum[3];
      if (total >= GS) atomicAdd(&group_len[b], 1);
    }
    return;
  }

  // Pass 1: in-radius flags, index order preserved via ballot
  for (int step = 0; step < 64; step++) {
    int i = step * 256 + tid;         // chunk = step*4 + wave, bit = lane
    bool flag = false;
    if (i < len) {
      float4 q = p[i];
      float d = dist2(cc.x, cc.y, cc.z, q.x, q.y, q.z);
      flag = d < 0.25f;               // radius^2, strict <
    }
    u64 m = __ballot(flag);
    if (lane == 0) masks[step * 4 + wave] = m;
  }
  __syncthreads();

  // Prefix scan over 256 chunk counts: shfl_up within wave + 4-wave offset
  u32 cnt = (u32)__popcll(masks[tid]);
  u32 s = cnt;
#pragma unroll
  for (int off = 1; off < 64; off <<= 1) {
    u32 o = __shfl_up(s, (unsigned)off, 64);
    if (lane >= off) s += o;
  }
  if (lane == 63) swsum[wave] = s;
  __syncthreads();
  u32 woff = 0;
#pragma unroll
  for (int w = 0; w < 4; w++) woff += (w < wave) ? swsum[w] : 0u;
  const u32 total = swsum[0] + swsum[1] + swsum[2] + swsum[3];
  const u32 incl = s + woff;          // block-inclusive prefix for chunk tid
  scnt[tid] = cnt;
  spre[tid] = incl;

  // Cap index T: index of the (UPK-1)-ranked in-radius point (first-512 rule)
  if (total > UPK) {
    u32 ex = incl - cnt;
    if (ex <= (UPK - 1) && incl > (UPK - 1)) {        // exactly one thread
      u32 r = (UPK - 1) - ex;
      u64 m = masks[tid];
      for (u32 k = 0; k < r; k++) m &= m - 1;
      s_T = tid * 64 + ((int)__ffsll((unsigned long long)m) - 1);
    }
  } else if (tid == 0) {
    s_T = NP - 1;
  }
  __syncthreads();                    // covers spre/scnt/s_T
  const int T = s_T;

  // Pass 2: compact (energy, idx) of candidates into LDS at exact rank
  for (int step = 0; step < 64; step++) {
    int i  = step * 256 + tid;
    int ch = step * 4 + wave;
    u64 m = masks[ch];
    if (((m >> lane) & 1ull) && i <= T) {
      u32 pos = ((spre[ch] - scnt[ch]) +
                 (u32)__popcll(m & ((1ull << lane) - 1ull))) & (UPK - 1);
      candE[pos] = ((const float*)p)[i * 4 + 3];   // energy channel
      candI[pos] = i;
    }
  }
  __syncthreads();

  const int ncand = (int)(total < UPK ? total : UPK);

  // Top-32 by (energy desc, pos asc): single wave, barrier-free rounds
  if (wave == 0) {
    u64 k[8];
#pragma unroll
    for (int t = 0; t < 8; t++) {
      int ci = lane + t * 64;
      k[t] = (ci < ncand) ? (((u64)fkey(candE[ci]) << 32) | (u32)(~ci)) : 0ull;
    }
    int pl = 0;
    for (int r = 0; r < GS; r++) {
      u64 bm = k[0];
#pragma unroll
      for (int t = 1; t < 8; t++) if (k[t] > bm) bm = k[t];
#pragma unroll
      for (int off = 32; off; off >>= 1) {
        u64 o = __shfl_xor(bm, (unsigned)off, 64);
        if (o > bm) bm = o;
      }
      if (bm == 0) break;             // wave-uniform: no candidates left
      int pos = (int)(~(u32)bm) & (UPK - 1);
      if (lane == 0) s_win[r] = candI[pos];
      int ol = pos & 63, ot = pos >> 6;
#pragma unroll
      for (int t = 0; t < 8; t++)     // kill winner (owner = lane ol, slot ot)
        if (t == ot && lane == ol) k[t] = 0;
      pl = r + 1;
    }
    if (lane == 0) {
      int f0 = (pl > 0) ? s_win[0] : 0;   // fill_empty_indices (pl>=1 always:
      for (int r = pl; r < GS; r++) s_win[r] = f0;  // center is in-radius)
      s_pl = pl;
    }
  }
  __syncthreads();

  const int base = b * CTX + g;
  if (tid < GS) {
    int fi = s_win[tid] & (NP - 1);
    float4 q = p[fi];
    ((float4*)out)[base * GS + tid] = q;
    out[OFF_PMASK + base * GS + tid] = (tid < s_pl) ? 1.0f : 0.0f;
  }
  if (tid == 0 && total >= GS) atomicAdd(&group_len[b], 1);
}

// ---------------------------------------------------------------------------
// Kernel 3: embedding mask from full-group counts
// ---------------------------------------------------------------------------
__global__ void emb_kernel(const int* __restrict__ group_len,
                           float* __restrict__ out)
{
  int i = blockIdx.x * blockDim.x + threadIdx.x;
  if (i < NB * CTX) {
    int b = i >> 8;
    int g = i & 255;
    out[OFF_EMB + i] = (g < group_len[b]) ? 1.0f : 0.0f;
  }
}

extern "C" void kernel_launch(void* const* d_in, const int* in_sizes, int n_in,
                              void* d_out, int out_size, void* d_ws, size_t ws_size,
                              hipStream_t stream)
{
  const float4* pts     = (const float4*)d_in[0];   // f32 (B,N,4)
  const int*    lengths = (const int*)d_in[1];
  float* out = (float*)d_out;

  char* ws = (char*)d_ws;
  float4* centers_ws = (float4*)(ws + WS_CENTERS);
  int*    group_len  = (int*)(ws + WS_GLEN);
  u64*    slots      = (u64*)(ws + WS_SLOT);
  u32*    cnts       = (u32*)(ws + WS_CNT);

  // Zero the sync slots + counters + group_len (ws is poisoned 0xAA each run)
  hipMemsetAsync(ws + WS_ZERO_FROM, 0, WS_ZERO_LEN, stream);

  fps_kernel<<<NB * FB, FPS_T, 0, stream>>>(pts, lengths, centers_ws,
                                            group_len, slots, cnts, out);
  group_kernel<<<NB * NG, BQ_T, 0, stream>>>(pts, lengths, centers_ws,
                                             group_len, out);
  emb_kernel<<<(NB * CTX + 255) / 256, 256, 0, stream>>>(group_len, out);
}

// Round 14
// 864.077 us; speedup vs baseline: 1.2398x; 1.2398x over previous
//
#include <hip/hip_runtime.h>
#include <stdint.h>

// Problem constants (match reference)
#define NB   8
#define NP   16384
#define NG   512      // NUM_GROUPS
#define GS   32       // GROUP_SIZE
#define UPK  512      // UPSCALE_K
#define CTX  256      // CONTEXT

// float32 output layout (flat element offsets):
// groups (8,256,32,4) | centers (8,256,4) | emb_mask (8,256) | point_mask (8,256,32)
#define OFF_CENTERS (NB*CTX*GS*4)            // 262144
#define OFF_EMB     (OFF_CENTERS + NB*CTX*4) // 270336
#define OFF_PMASK   (OFF_EMB + NB*CTX)       // 272384

typedef unsigned long long u64;
typedef unsigned int u32;
typedef float v2f __attribute__((ext_vector_type(2)));

// Monotonic float->uint key (full-range; needed for energies which can be <0)
__device__ __forceinline__ u32 fkey(float f) {
  union { float f; u32 u; } v; v.f = f;
  u32 s = v.u;
  return s ^ ((s & 0x80000000u) ? 0xFFFFFFFFu : 0x80000000u);
}

// Strictly-unfused f32 squared distance, op order = np: ((dx*dx+dy*dy)+dz*dz).
// _rn intrinsics forbid FMA contraction (hipcc defaults -ffp-contract=fast).
__device__ __forceinline__ float dist2(float ax, float ay, float az,
                                       float bx, float by, float bz) {
  float dx = __fsub_rn(ax, bx);
  float dy = __fsub_rn(ay, by);
  float dz = __fsub_rn(az, bz);
  return __fadd_rn(__fadd_rn(__fmul_rn(dx, dx), __fmul_rn(dy, dy)),
                   __fmul_rn(dz, dz));
}

// u64 max-combine with a DPP-moved copy (bound_ctrl=false keeps own value
// for invalid sources -> max no-op there). Proven since R8 (absmax 0).
template<int CTRL, int RM>
__device__ __forceinline__ u64 dpp_max_u64(u64 k) {
  int lo = (int)(u32)k, hi = (int)(u32)(k >> 32);
  int mlo = __builtin_amdgcn_update_dpp(lo, lo, CTRL, RM, 0xf, false);
  int mhi = __builtin_amdgcn_update_dpp(hi, hi, CTRL, RM, 0xf, false);
  u64 o = ((u64)(u32)mhi << 32) | (u32)mlo;
  return o > k ? o : k;
}

__device__ __forceinline__ u64 wave_max_u64(u64 k) {
  k = dpp_max_u64<0x111, 0xf>(k);   // row_shr:1
  k = dpp_max_u64<0x112, 0xf>(k);   // row_shr:2
  k = dpp_max_u64<0x114, 0xf>(k);   // row_shr:4
  k = dpp_max_u64<0x118, 0xf>(k);   // row_shr:8
  k = dpp_max_u64<0x142, 0xa>(k);   // row_bcast:15
  k = dpp_max_u64<0x143, 0xc>(k);   // row_bcast:31 -> lane63 = wave max
  return k;
}

__device__ __forceinline__ u64 read_lane_u64(u64 k, int lane) {
  u32 lo = (u32)__builtin_amdgcn_readlane((int)(u32)k, lane);
  u32 hi = (u32)__builtin_amdgcn_readlane((int)(u32)(k >> 32), lane);
  return ((u64)hi << 32) | lo;
}

// ---------------------------------------------------------------------------
// Kernel 1: farthest point sampling. R12's proven config (734 us total):
// one 512-thread block per batch (8 waves = 2/SIMD), amdgpu_waves_per_eu(2,2)
// -> 256-VGPR budget, arrays in arch VGPRs (R12 counter: VGPR 100 vs 40).
// Single change vs R12: inner loop uses float2 ext-vector arithmetic under
// `fp contract(off)` (R11-verified bit-exact semantics: per-op IEEE-rn,
// np op order ((x+y)+z) per element) so ISel can form v_pk_add/mul_f32 on
// properly-allocated pairs — 8 pk instr per point-pair vs 16 scalar.
// Argmax: per-element strict > in ascending j order = np.argmax first
// occurrence; cross-thread tie-break via ~gidx in the u64 key. Invalid
// points alias p[0] -> mind == 0 from iter 1, never win. Distances >= 0,
// no NaN -> f32 bits u32-monotonic.
// ---------------------------------------------------------------------------
#define FPS_T 512
#define PPT   (NP / FPS_T)   // 32 points per thread, 16 pairs

__global__ __launch_bounds__(FPS_T)
__attribute__((amdgpu_waves_per_eu(2, 2)))
void fps_kernel(const float4* __restrict__ pts, const int* __restrict__ lengths,
                float4* __restrict__ centers_ws, int* __restrict__ group_len,
                float* __restrict__ out)
{
#pragma clang fp contract(off)
  const int b    = blockIdx.x;
  const int tid  = threadIdx.x;
  const int lane = tid & 63;
  const int wave = tid >> 6;           // 8 waves
  const float4* p = pts + (size_t)b * NP;
  const int len = lengths[b];
  if (tid == 0) group_len[b] = 0;

  const float4 q0 = p[0];
  v2f px2[PPT/2], py2[PPT/2], pz2[PPT/2], mind2[PPT/2];
#pragma unroll
  for (int h = 0; h < PPT/2; h++) {
    int ia = tid + (2*h) * FPS_T, ib = tid + (2*h+1) * FPS_T;
    float4 qa = p[ia]; if (ia >= len) qa = q0;   // invalid -> alias of p[0]
    float4 qb = p[ib]; if (ib >= len) qb = q0;
    px2[h] = (v2f){qa.x, qb.x};
    py2[h] = (v2f){qa.y, qb.y};
    pz2[h] = (v2f){qa.z, qb.z};
    mind2[h] = (v2f){1e10f, 1e10f};
  }

  __shared__ u64 sred[2][8];          // parity-buffered -> 1 barrier/step
  __shared__ int s_centers[NG];
  if (tid == 0) s_centers[0] = 0;     // start index = 0

  int last = 0;
  for (int it = 1; it < NG; it++) {
    float4 lp = p[last];              // uniform -> scalar load, L2-served
    v2f lx = (v2f){lp.x, lp.x};
    v2f ly = (v2f){lp.y, lp.y};
    v2f lz = (v2f){lp.z, lp.z};
    float tmax = -1.0f; int tj = 0;
#pragma unroll
    for (int h = 0; h < PPT/2; h++) {
      v2f dx = px2[h] - lx;           // contract(off): separate IEEE-rn ops
      v2f dy = py2[h] - ly;
      v2f dz = pz2[h] - lz;
      v2f d2 = dx*dx + dy*dy + dz*dz; // parses ((x+y)+z), np order
      float mx = fminf(mind2[h].x, d2.x);
      float my = fminf(mind2[h].y, d2.y);
      mind2[h].x = mx;
      mind2[h].y = my;
      bool ca = mx > tmax;            // strict > keeps earliest j
      tmax = ca ? mx : tmax;
      tj   = ca ? (2*h) : tj;
      bool cb = my > tmax;
      tmax = cb ? my : tmax;
      tj   = cb ? (2*h+1) : tj;
    }
    int gidx = tid + (tj << 9);       // j asc => global idx asc within thread
    u64 key = ((u64)__float_as_uint(tmax) << 32) | (u32)(~gidx);
    key = wave_max_u64(key);          // lane 63 = wave winner
    u64 wkey = read_lane_u64(key, 63);
    if (lane == 0) sred[it & 1][wave] = wkey;
    __syncthreads();                  // single barrier per iteration
    u64 k2 = sred[it & 1][lane & 7];  // 8 slots replicated every 8 lanes
    k2 = dpp_max_u64<0x111, 0xf>(k2); // row_shr:1
    k2 = dpp_max_u64<0x112, 0xf>(k2); // row_shr:2
    k2 = dpp_max_u64<0x114, 0xf>(k2); // row_shr:4 -> lane7 = max of slots 0..7
    u64 bk = read_lane_u64(k2, 7);
    last = (int)(~(u32)bk) & (NP - 1);
    if (tid == 0) s_centers[it] = last;
  }
  __syncthreads();

  // FPS_T == NG == 512: one center per thread
  {
    int ci = s_centers[tid] & (NP - 1);
    float4 q = p[ci];
    centers_ws[b * NG + tid] = q;
    if (tid < CTX) {
      ((float4*)(out + OFF_CENTERS))[b * CTX + tid] = q;
    }
  }
}

// ---------------------------------------------------------------------------
// Kernel 2: ball query (first-512-by-index candidates, strict-f32 test)
// + top-32 by energy. Swizzled so batch b owns XCD b (blk&7) -> per-XCD
// L2-resident point data. g >= CTX groups take a count-only fast path.
// Heavy path: ballot masks -> shfl_up prefix scan (1 barrier) -> compact ->
// single-wave barrier-free top-32 (u64 key = fkeyE<<32 | ~pos).
// ---------------------------------------------------------------------------
#define BQ_T 256

__global__ __launch_bounds__(BQ_T)
void group_kernel(const float4* __restrict__ pts, const int* __restrict__ lengths,
                  const float4* __restrict__ centers_ws, int* __restrict__ group_len,
                  float* __restrict__ out)
{
  const int blk  = blockIdx.x;
  const int b    = blk & (NB - 1);    // XCD affinity (blockIdx % 8 round-robin)
  const int g    = blk >> 3;
  const int tid  = threadIdx.x;
  const int lane = tid & 63;
  const int wave = tid >> 6;
  const float4* p = pts + (size_t)b * NP;
  const int len = lengths[b];
  const float4 cc = centers_ws[b * NG + g];

  __shared__ u64 masks[256];          // per-64-chunk in-radius bitmasks
  __shared__ u32 scnt[256];
  __shared__ u32 spre[256];
  __shared__ u32 swsum[4];
  __shared__ float candE[UPK];
  __shared__ int   candI[UPK];
  __shared__ int   s_T, s_pl;
  __shared__ int   s_win[GS];

  if (g >= CTX) {                     // count-only: is this group full?
    u32 c = 0;
    for (int step = 0; step < 64; step++) {
      int i = step * 256 + tid;
      if (i < len) {
        float4 q = p[i];
        float d = dist2(cc.x, cc.y, cc.z, q.x, q.y, q.z);
        c += (d < 0.25f) ? 1u : 0u;
      }
    }
#pragma unroll
    for (int off = 32; off; off >>= 1) c += __shfl_down(c, (unsigned)off, 64);
    if (lane == 0) swsum[wave] = c;
    __syncthreads();
    if (tid == 0) {
      u32 total = swsum[0] + swsum[1] + swsum[2] + swsum[3];
      if (total >= GS) atomicAdd(&group_len[b], 1);
    }
    return;
  }

  // Pass 1: in-radius flags, index order preserved via ballot
  for (int step = 0; step < 64; step++) {
    int i = step * 256 + tid;         // chunk = step*4 + wave, bit = lane
    bool flag = false;
    if (i < len) {
      float4 q = p[i];
      float d = dist2(cc.x, cc.y, cc.z, q.x, q.y, q.z);
      flag = d < 0.25f;               // radius^2, strict <
    }
    u64 m = __ballot(flag);
    if (lane == 0) masks[step * 4 + wave] = m;
  }
  __syncthreads();

  // Prefix scan over 256 chunk counts: shfl_up within wave + 4-wave offset
  u32 cnt = (u32)__popcll(masks[tid]);
  u32 s = cnt;
#pragma unroll
  for (int off = 1; off < 64; off <<= 1) {
    u32 o = __shfl_up(s, (unsigned)off, 64);
    if (lane >= off) s += o;
  }
  if (lane == 63) swsum[wave] = s;
  __syncthreads();
  u32 woff = 0;
#pragma unroll
  for (int w = 0; w < 4; w++) woff += (w < wave) ? swsum[w] : 0u;
  const u32 total = swsum[0] + swsum[1] + swsum[2] + swsum[3];
  const u32 incl = s + woff;          // block-inclusive prefix for chunk tid
  scnt[tid] = cnt;
  spre[tid] = incl;

  // Cap index T: index of the (UPK-1)-ranked in-radius point (first-512 rule)
  if (total > UPK) {
    u32 ex = incl - cnt;
    if (ex <= (UPK - 1) && incl > (UPK - 1)) {        // exactly one thread
      u32 r = (UPK - 1) - ex;
      u64 m = masks[tid];
      for (u32 k = 0; k < r; k++) m &= m - 1;
      s_T = tid * 64 + ((int)__ffsll((unsigned long long)m) - 1);
    }
  } else if (tid == 0) {
    s_T = NP - 1;
  }
  __syncthreads();                    // covers spre/scnt/s_T
  const int T = s_T;

  // Pass 2: compact (energy, idx) of candidates into LDS at exact rank
  for (int step = 0; step < 64; step++) {
    int i  = step * 256 + tid;
    int ch = step * 4 + wave;
    u64 m = masks[ch];
    if (((m >> lane) & 1ull) && i <= T) {
      u32 pos = ((spre[ch] - scnt[ch]) +
                 (u32)__popcll(m & ((1ull << lane) - 1ull))) & (UPK - 1);
      candE[pos] = ((const float*)p)[i * 4 + 3];   // energy channel
      candI[pos] = i;
    }
  }
  __syncthreads();

  const int ncand = (int)(total < UPK ? total : UPK);

  // Top-32 by (energy desc, pos asc): single wave, barrier-free rounds
  if (wave == 0) {
    u64 k[8];
#pragma unroll
    for (int t = 0; t < 8; t++) {
      int ci = lane + t * 64;
      k[t] = (ci < ncand) ? (((u64)fkey(candE[ci]) << 32) | (u32)(~ci)) : 0ull;
    }
    int pl = 0;
    for (int r = 0; r < GS; r++) {
      u64 bm = k[0];
#pragma unroll
      for (int t = 1; t < 8; t++) if (k[t] > bm) bm = k[t];
#pragma unroll
      for (int off = 32; off; off >>= 1) {
        u64 o = __shfl_xor(bm, (unsigned)off, 64);
        if (o > bm) bm = o;
      }
      if (bm == 0) break;             // wave-uniform: no candidates left
      int pos = (int)(~(u32)bm) & (UPK - 1);
      if (lane == 0) s_win[r] = candI[pos];
      int ol = pos & 63, ot = pos >> 6;
#pragma unroll
      for (int t = 0; t < 8; t++)     // kill winner (owner = lane ol, slot ot)
        if (t == ot && lane == ol) k[t] = 0;
      pl = r + 1;
    }
    if (lane == 0) {
      int f0 = (pl > 0) ? s_win[0] : 0;   // fill_empty_indices (pl>=1 always:
      for (int r = pl; r < GS; r++) s_win[r] = f0;  // center is in-radius)
      s_pl = pl;
    }
  }
  __syncthreads();

  const int base = b * CTX + g;
  if (tid < GS) {
    int fi = s_win[tid] & (NP - 1);
    float4 q = p[fi];
    ((float4*)out)[base * GS + tid] = q;
    out[OFF_PMASK + base * GS + tid] = (tid < s_pl) ? 1.0f : 0.0f;
  }
  if (tid == 0 && total >= GS) atomicAdd(&group_len[b], 1);
}

// ---------------------------------------------------------------------------
// Kernel 3: embedding mask from full-group counts
// ---------------------------------------------------------------------------
__global__ void emb_kernel(const int* __restrict__ group_len,
                           float* __restrict__ out)
{
  int i = blockIdx.x * blockDim.x + threadIdx.x;
  if (i < NB * CTX) {
    int b = i >> 8;
    int g = i & 255;
    out[OFF_EMB + i] = (g < group_len[b]) ? 1.0f : 0.0f;
  }
}

extern "C" void kernel_launch(void* const* d_in, const int* in_sizes, int n_in,
                              void* d_out, int out_size, void* d_ws, size_t ws_size,
                              hipStream_t stream)
{
  const float4* pts     = (const float4*)d_in[0];   // f32 (B,N,4)
  const int*    lengths = (const int*)d_in[1];
  float* out = (float*)d_out;

  float4* centers_ws = (float4*)d_ws;               // 8*512*16 B = 64 KB
  int*    group_len  = (int*)((char*)d_ws + (size_t)NB * NG * sizeof(float4));

  fps_kernel<<<NB, FPS_T, 0, stream>>>(pts, lengths, centers_ws, group_len, out);
  group_kernel<<<NB * NG, BQ_T, 0, stream>>>(pts, lengths, centers_ws, group_len, out);
  emb_kernel<<<(NB * CTX + 255) / 256, 256, 0, stream>>>(group_len, out);
}

// Round 16
// 733.681 us; speedup vs baseline: 1.4601x; 1.1777x over previous
//
#include <hip/hip_runtime.h>
#include <stdint.h>

// Problem constants (match reference)
#define NB   8
#define NP   16384
#define NG   512      // NUM_GROUPS
#define GS   32       // GROUP_SIZE
#define UPK  512      // UPSCALE_K
#define CTX  256      // CONTEXT

// float32 output layout (flat element offsets):
// groups (8,256,32,4) | centers (8,256,4) | emb_mask (8,256) | point_mask (8,256,32)
#define OFF_CENTERS (NB*CTX*GS*4)            // 262144
#define OFF_EMB     (OFF_CENTERS + NB*CTX*4) // 270336
#define OFF_PMASK   (OFF_EMB + NB*CTX)       // 272384

typedef unsigned long long u64;
typedef unsigned int u32;

// Monotonic float->uint key (full-range; needed for energies which can be <0)
__device__ __forceinline__ u32 fkey(float f) {
  union { float f; u32 u; } v; v.f = f;
  u32 s = v.u;
  return s ^ ((s & 0x80000000u) ? 0xFFFFFFFFu : 0x80000000u);
}

// Strictly-unfused f32 squared distance, op order = np: ((dx*dx+dy*dy)+dz*dz).
// _rn intrinsics forbid FMA contraction (hipcc defaults -ffp-contract=fast).
// NOTE (R15 post-mortem): the algebraic FMA form ||p||^2-2p.c+||c||^2 broke
// selection (absmax 2.26) — its few-ulp-of-||p||^2 error flips argmax /
// membership decisions. This unfused difference form is load-bearing.
__device__ __forceinline__ float dist2(float ax, float ay, float az,
                                       float bx, float by, float bz) {
  float dx = __fsub_rn(ax, bx);
  float dy = __fsub_rn(ay, by);
  float dz = __fsub_rn(az, bz);
  return __fadd_rn(__fadd_rn(__fmul_rn(dx, dx), __fmul_rn(dy, dy)),
                   __fmul_rn(dz, dz));
}

// u64 max-combine with a DPP-moved copy (bound_ctrl=false keeps own value
// for invalid sources -> max no-op there). Proven since R8 (absmax 0).
template<int CTRL, int RM>
__device__ __forceinline__ u64 dpp_max_u64(u64 k) {
  int lo = (int)(u32)k, hi = (int)(u32)(k >> 32);
  int mlo = __builtin_amdgcn_update_dpp(lo, lo, CTRL, RM, 0xf, false);
  int mhi = __builtin_amdgcn_update_dpp(hi, hi, CTRL, RM, 0xf, false);
  u64 o = ((u64)(u32)mhi << 32) | (u32)mlo;
  return o > k ? o : k;
}

__device__ __forceinline__ u64 wave_max_u64(u64 k) {
  k = dpp_max_u64<0x111, 0xf>(k);   // row_shr:1
  k = dpp_max_u64<0x112, 0xf>(k);   // row_shr:2
  k = dpp_max_u64<0x114, 0xf>(k);   // row_shr:4
  k = dpp_max_u64<0x118, 0xf>(k);   // row_shr:8
  k = dpp_max_u64<0x142, 0xa>(k);   // row_bcast:15
  k = dpp_max_u64<0x143, 0xc>(k);   // row_bcast:31 -> lane63 = wave max
  return k;
}

__device__ __forceinline__ u64 read_lane_u64(u64 k, int lane) {
  u32 lo = (u32)__builtin_amdgcn_readlane((int)(u32)k, lane);
  u32 hi = (u32)__builtin_amdgcn_readlane((int)(u32)(k >> 32), lane);
  return ((u64)hi << 32) | lo;
}

// ---------------------------------------------------------------------------
// Kernel 1: farthest point sampling (R12 — best measured: fps 627 us).
// One 512-thread block per batch (8 waves = 2/SIMD); amdgpu_waves_per_eu(2,2)
// pins 1 block/CU with a 256-VGPR budget so the 32-point/thread arrays live
// in arch VGPRs (VGPR_Count 100; the 1024-thread variants spilled at 40-64).
// 511 sequential argmax steps; strictly-unfused f32 distances; fminf running
// min; per-thread strict > ascending-j argmax (= np.argmax first occurrence);
// cross-thread tie-break via ~gidx in the u64 key; single barrier/iter with
// parity-buffered LDS slots; wave + block reduce via u64 DPP max.
// Invalid points alias p[0] -> mind == 0 from iter 1, never win.
// Distances >= 0, no NaN -> f32 bits u32-monotonic.
// Structural notes from the search: multi-block + device-atomic handshake
// costs +2000 cyc/iter (R13); two-barrier argmax +400 (R9); packed-f32
// (asm or ISel) loses to scalar (R9/R10/R14); FMA algebra breaks bit-exact
// selection (R15). This shape is the practical floor.
// ---------------------------------------------------------------------------
#define FPS_T 512
#define PPT   (NP / FPS_T)   // 32 points per thread

__global__ __launch_bounds__(FPS_T)
__attribute__((amdgpu_waves_per_eu(2, 2)))
void fps_kernel(const float4* __restrict__ pts, const int* __restrict__ lengths,
                float4* __restrict__ centers_ws, int* __restrict__ group_len,
                float* __restrict__ out)
{
  const int b    = blockIdx.x;
  const int tid  = threadIdx.x;
  const int lane = tid & 63;
  const int wave = tid >> 6;           // 8 waves
  const float4* p = pts + (size_t)b * NP;
  const int len = lengths[b];
  if (tid == 0) group_len[b] = 0;

  const float4 q0 = p[0];
  float px[PPT], py[PPT], pz[PPT], mind[PPT];
#pragma unroll
  for (int j = 0; j < PPT; j++) {
    int i = tid + j * FPS_T;          // strided ownership -> coalesced loads
    float4 q = p[i];
    if (i >= len) q = q0;             // invalid -> alias of p[0]
    px[j] = q.x; py[j] = q.y; pz[j] = q.z;
    mind[j] = 1e10f;
  }

  __shared__ u64 sred[2][8];          // parity-buffered -> 1 barrier/step
  __shared__ int s_centers[NG];
  if (tid == 0) s_centers[0] = 0;     // start index = 0

  int last = 0;
  for (int it = 1; it < NG; it++) {
    float4 lp = p[last];              // uniform -> scalar load, L2-served
    float tmax = -1.0f; int tj = 0;
#pragma unroll
    for (int j = 0; j < PPT; j++) {
      float d = dist2(px[j], py[j], pz[j], lp.x, lp.y, lp.z);
      float m = fminf(mind[j], d);
      mind[j] = m;
      bool c = m > tmax;              // strict > keeps earliest j
      tmax = c ? m : tmax;
      tj   = c ? j : tj;
    }
    int gidx = tid + (tj << 9);       // j asc => global idx asc within thread
    u64 key = ((u64)__float_as_uint(tmax) << 32) | (u32)(~gidx);
    key = wave_max_u64(key);          // lane 63 = wave winner
    u64 wkey = read_lane_u64(key, 63);
    if (lane == 0) sred[it & 1][wave] = wkey;
    __syncthreads();                  // single barrier per iteration
    u64 k2 = sred[it & 1][lane & 7];  // 8 slots replicated every 8 lanes
    k2 = dpp_max_u64<0x111, 0xf>(k2); // row_shr:1
    k2 = dpp_max_u64<0x112, 0xf>(k2); // row_shr:2
    k2 = dpp_max_u64<0x114, 0xf>(k2); // row_shr:4 -> lane7 = max of slots 0..7
    u64 bk = read_lane_u64(k2, 7);
    last = (int)(~(u32)bk) & (NP - 1);
    if (tid == 0) s_centers[it] = last;
  }
  __syncthreads();

  // FPS_T == NG == 512: one center per thread
  {
    int ci = s_centers[tid] & (NP - 1);
    float4 q = p[ci];
    centers_ws[b * NG + tid] = q;
    if (tid < CTX) {
      ((float4*)(out + OFF_CENTERS))[b * CTX + tid] = q;
    }
  }
}

// ---------------------------------------------------------------------------
// Kernel 2: ball query (first-512-by-index candidates, strict-f32 test)
// + top-32 by energy. Swizzled so batch b owns XCD b (blk&7) -> per-XCD
// L2-resident point data. g >= CTX groups take a count-only fast path.
// Heavy path: ballot masks -> shfl_up prefix scan (1 barrier) -> compact ->
// single-wave barrier-free top-32 (u64 key = fkeyE<<32 | ~pos).
// ---------------------------------------------------------------------------
#define BQ_T 256

__global__ __launch_bounds__(BQ_T)
void group_kernel(const float4* __restrict__ pts, const int* __restrict__ lengths,
                  const float4* __restrict__ centers_ws, int* __restrict__ group_len,
                  float* __restrict__ out)
{
  const int blk  = blockIdx.x;
  const int b    = blk & (NB - 1);    // XCD affinity (blockIdx % 8 round-robin)
  const int g    = blk >> 3;
  const int tid  = threadIdx.x;
  const int lane = tid & 63;
  const int wave = tid >> 6;
  const float4* p = pts + (size_t)b * NP;
  const int len = lengths[b];
  const float4 cc = centers_ws[b * NG + g];

  __shared__ u64 masks[256];          // per-64-chunk in-radius bitmasks
  __shared__ u32 scnt[256];
  __shared__ u32 spre[256];
  __shared__ u32 swsum[4];
  __shared__ float candE[UPK];
  __shared__ int   candI[UPK];
  __shared__ int   s_T, s_pl;
  __shared__ int   s_win[GS];

  if (g >= CTX) {                     // count-only: is this group full?
    u32 c = 0;
    for (int step = 0; step < 64; step++) {
      int i = step * 256 + tid;
      if (i < len) {
        float4 q = p[i];
        float d = dist2(cc.x, cc.y, cc.z, q.x, q.y, q.z);
        c += (d < 0.25f) ? 1u : 0u;
      }
    }
#pragma unroll
    for (int off = 32; off; off >>= 1) c += __shfl_down(c, (unsigned)off, 64);
    if (lane == 0) swsum[wave] = c;
    __syncthreads();
    if (tid == 0) {
      u32 total = swsum[0] + swsum[1] + swsum[2] + swsum[3];
      if (total >= GS) atomicAdd(&group_len[b], 1);
    }
    return;
  }

  // Pass 1: in-radius flags, index order preserved via ballot
  for (int step = 0; step < 64; step++) {
    int i = step * 256 + tid;         // chunk = step*4 + wave, bit = lane
    bool flag = false;
    if (i < len) {
      float4 q = p[i];
      float d = dist2(cc.x, cc.y, cc.z, q.x, q.y, q.z);
      flag = d < 0.25f;               // radius^2, strict <
    }
    u64 m = __ballot(flag);
    if (lane == 0) masks[step * 4 + wave] = m;
  }
  __syncthreads();

  // Prefix scan over 256 chunk counts: shfl_up within wave + 4-wave offset
  u32 cnt = (u32)__popcll(masks[tid]);
  u32 s = cnt;
#pragma unroll
  for (int off = 1; off < 64; off <<= 1) {
    u32 o = __shfl_up(s, (unsigned)off, 64);
    if (lane >= off) s += o;
  }
  if (lane == 63) swsum[wave] = s;
  __syncthreads();
  u32 woff = 0;
#pragma unroll
  for (int w = 0; w < 4; w++) woff += (w < wave) ? swsum[w] : 0u;
  const u32 total = swsum[0] + swsum[1] + swsum[2] + swsum[3];
  const u32 incl = s + woff;          // block-inclusive prefix for chunk tid
  scnt[tid] = cnt;
  spre[tid] = incl;

  // Cap index T: index of the (UPK-1)-ranked in-radius point (first-512 rule)
  if (total > UPK) {
    u32 ex = incl - cnt;
    if (ex <= (UPK - 1) && incl > (UPK - 1)) {        // exactly one thread
      u32 r = (UPK - 1) - ex;
      u64 m = masks[tid];
      for (u32 k = 0; k < r; k++) m &= m - 1;
      s_T = tid * 64 + ((int)__ffsll((unsigned long long)m) - 1);
    }
  } else if (tid == 0) {
    s_T = NP - 1;
  }
  __syncthreads();                    // covers spre/scnt/s_T
  const int T = s_T;

  // Pass 2: compact (energy, idx) of candidates into LDS at exact rank
  for (int step = 0; step < 64; step++) {
    int i  = step * 256 + tid;
    int ch = step * 4 + wave;
    u64 m = masks[ch];
    if (((m >> lane) & 1ull) && i <= T) {
      u32 pos = ((spre[ch] - scnt[ch]) +
                 (u32)__popcll(m & ((1ull << lane) - 1ull))) & (UPK - 1);
      candE[pos] = ((const float*)p)[i * 4 + 3];   // energy channel
      candI[pos] = i;
    }
  }
  __syncthreads();

  const int ncand = (int)(total < UPK ? total : UPK);

  // Top-32 by (energy desc, pos asc): single wave, barrier-free rounds
  if (wave == 0) {
    u64 k[8];
#pragma unroll
    for (int t = 0; t < 8; t++) {
      int ci = lane + t * 64;
      k[t] = (ci < ncand) ? (((u64)fkey(candE[ci]) << 32) | (u32)(~ci)) : 0ull;
    }
    int pl = 0;
    for (int r = 0; r < GS; r++) {
      u64 bm = k[0];
#pragma unroll
      for (int t = 1; t < 8; t++) if (k[t] > bm) bm = k[t];
#pragma unroll
      for (int off = 32; off; off >>= 1) {
        u64 o = __shfl_xor(bm, (unsigned)off, 64);
        if (o > bm) bm = o;
      }
      if (bm == 0) break;             // wave-uniform: no candidates left
      int pos = (int)(~(u32)bm) & (UPK - 1);
      if (lane == 0) s_win[r] = candI[pos];
      int ol = pos & 63, ot = pos >> 6;
#pragma unroll
      for (int t = 0; t < 8; t++)     // kill winner (owner = lane ol, slot ot)
        if (t == ot && lane == ol) k[t] = 0;
      pl = r + 1;
    }
    if (lane == 0) {
      int f0 = (pl > 0) ? s_win[0] : 0;   // fill_empty_indices (pl>=1 always:
      for (int r = pl; r < GS; r++) s_win[r] = f0;  // center is in-radius)
      s_pl = pl;
    }
  }
  __syncthreads();

  const int base = b * CTX + g;
  if (tid < GS) {
    int fi = s_win[tid] & (NP - 1);
    float4 q = p[fi];
    ((float4*)out)[base * GS + tid] = q;
    out[OFF_PMASK + base * GS + tid] = (tid < s_pl) ? 1.0f : 0.0f;
  }
  if (tid == 0 && total >= GS) atomicAdd(&group_len[b], 1);
}

// ---------------------------------------------------------------------------
// Kernel 3: embedding mask from full-group counts
// ---------------------------------------------------------------------------
__global__ void emb_kernel(const int* __restrict__ group_len,
                           float* __restrict__ out)
{
  int i = blockIdx.x * blockDim.x + threadIdx.x;
  if (i < NB * CTX) {
    int b = i >> 8;
    int g = i & 255;
    out[OFF_EMB + i] = (g < group_len[b]) ? 1.0f : 0.0f;
  }
}

extern "C" void kernel_launch(void* const* d_in, const int* in_sizes, int n_in,
                              void* d_out, int out_size, void* d_ws, size_t ws_size,
                              hipStream_t stream)
{
  const float4* pts     = (const float4*)d_in[0];   // f32 (B,N,4)
  const int*    lengths = (const int*)d_in[1];
  float* out = (float*)d_out;

  float4* centers_ws = (float4*)d_ws;               // 8*512*16 B = 64 KB
  int*    group_len  = (int*)((char*)d_ws + (size_t)NB * NG * sizeof(float4));

  fps_kernel<<<NB, FPS_T, 0, stream>>>(pts, lengths, centers_ws, group_len, out);
  group_kernel<<<NB * NG, BQ_T, 0, stream>>>(pts, lengths, centers_ws, group_len, out);
  emb_kernel<<<(NB * CTX + 255) / 256, 256, 0, stream>>>(group_len, out);
}